// Round 14
// baseline (110.380 us; speedup 1.0000x reference)
//
#include <hip/hip_runtime.h>
#include <math.h>

#define B   8
#define NA  33600
#define M   64
#define NC  80
#define KK  13
#define EPSF 1e-9f
#define PIF 3.14159265358979323846f

#define NPOS 1536          // positive-metric capacity (<= in-circle max ~1100)
#define NBM  (B * M)       // 512
#define SPB  (M * KK)      // 832 winner slots per batch

// ---------------------------------------------------------------- helpers

__device__ __forceinline__ float circle_iou(float gx, float gy, float gr,
                                            float px, float py, float pr) {
    float dx = gx - px, dy = gy - py;
    float d  = sqrtf(dx * dx + dy * dy + 1e-12f);
    float r0sq = gr * gr, r1sq = pr * pr;
    float d1 = (r0sq - r1sq + d * d) / (2.0f * d);
    float d2 = d - d1;
    float t0 = fminf(fmaxf(d1 / fmaxf(gr, EPSF), -1.0f), 1.0f);
    float t1 = fminf(fmaxf(d2 / fmaxf(pr, EPSF), -1.0f), 1.0f);
    float a0 = r0sq * acosf(t0) - d1 * sqrtf(fmaxf(r0sq - d1 * d1, 0.0f));
    float a1 = r1sq * acosf(t1) - d2 * sqrtf(fmaxf(r1sq - d2 * d2, 0.0f));
    float lens = a0 + a1;
    float rmin = fminf(gr, pr);
    float contained = PIF * rmin * rmin;
    float inter = (d >= gr + pr) ? 0.0f
                : ((d <= fabsf(gr - pr)) ? contained : lens);
    float uni = PIF * r0sq + PIF * r1sq - inter;
    return (uni > 0.0f) ? inter / uni : 0.0f;
}

// ---------------------------------------------------------------- K1: per-gt dense-stream discovery + top-13
// 4-anchor unroll: 5 float4 loads per 4 anchors (load-issue bound phase).
// Winners carry (anchor, met, ov). Also inits assigned/am_val/pos arrays.

__global__ __launch_bounds__(1024)
void k_discover(const float* __restrict__ pd_scores, const float* __restrict__ pd_circles,
                const float* __restrict__ anc, const int* __restrict__ gt_labels,
                const float* __restrict__ gt_circles, const float* __restrict__ mask_gt,
                int* __restrict__ wlist, float* __restrict__ wmet, float* __restrict__ wov,
                int* __restrict__ assigned, float* __restrict__ am_val,
                int* __restrict__ pos_align_i, int* __restrict__ pos_ov_i) {
    int bm = blockIdx.x;
    int b  = bm / M;
    int m  = bm - b * M;
    int tid = threadIdx.x;

    // init disjoint slice of assigned/am_val + pos arrays (m==0 blocks)
    const int SL = (B * NA) / NBM;             // 525
    int s0 = bm * SL;
    if (tid < SL) { assigned[s0 + tid] = -1; am_val[s0 + tid] = 0.0f; }
    if (m == 0 && tid < M) { pos_align_i[b * M + tid] = 0; pos_ov_i[b * M + tid] = 0; }

    __shared__ int   s_pcnt;
    __shared__ int   s_pa[NPOS];
    __shared__ float s_pv[NPOS];
    __shared__ float s_po[NPOS];
    __shared__ int   s_win[KK];
    __shared__ float s_selv[KK], s_selo[KK];

    float gmask = mask_gt[bm];
    if (!(gmask > 0.0f)) {                     // inactive gt: empty winner list
        if (tid < KK) wlist[bm * KK + tid] = -1;
        return;
    }

    float gx = gt_circles[bm * 3 + 0];
    float gy = gt_circles[bm * 3 + 1];
    float gr = gt_circles[bm * 3 + 2];
    int gl = gt_labels[bm];
    gl = gl < 0 ? 0 : (gl > NC - 1 ? NC - 1 : gl);

    if (tid == 0) s_pcnt = 0;
    __syncthreads();

#define PROC(A_, AX_, AY_, PX_, PY_, PR_) do {                                 \
        float dxa_ = (AX_) - gx, dya_ = (AY_) - gy;                            \
        if (sqrtf(dxa_ * dxa_ + dya_ * dya_) < gr) {                           \
            float cdx_ = gx - (PX_), cdy_ = gy - (PY_);                        \
            float dc_ = sqrtf(cdx_ * cdx_ + cdy_ * cdy_ + 1e-12f);             \
            if (dc_ < gr + (PR_)) {                                            \
                float ov_ = circle_iou(gx, gy, gr, (PX_), (PY_), (PR_));       \
                if (ov_ > 0.0f) {                                              \
                    float sc_ = pd_scores[((size_t)b * NA + (A_)) * NC + gl];  \
                    float o2_ = ov_ * ov_;                                     \
                    float met_ = sc_ * (o2_ * o2_ * o2_);                      \
                    if (met_ > 0.0f) {                                         \
                        int p_ = atomicAdd(&s_pcnt, 1);                        \
                        if (p_ < NPOS) { s_pa[p_] = (A_); s_pv[p_] = met_; s_po[p_] = ov_; } \
                    } } } } } while (0)

    // dense stream: 4 anchors / iter; 2 anc float4 + 3 pd float4 (all aligned)
    const float4* anc4 = reinterpret_cast<const float4*>(anc);
    const float4* pdc4 = reinterpret_cast<const float4*>(pd_circles + (size_t)b * NA * 3);
    for (int q = tid; q < NA / 4; q += 1024) {
        float4 a01 = anc4[2 * q];
        float4 a23 = anc4[2 * q + 1];
        float4 f0 = pdc4[3 * q + 0];   // r0: x y z | r1: x
        float4 f1 = pdc4[3 * q + 1];   // r1: y z | r2: x y
        float4 f2 = pdc4[3 * q + 2];   // r2: z | r3: x y z
        PROC(4 * q,     a01.x, a01.y, f0.x, f0.y, f0.z);
        PROC(4 * q + 1, a01.z, a01.w, f0.w, f1.x, f1.y);
        PROC(4 * q + 2, a23.x, a23.y, f1.z, f1.w, f2.x);
        PROC(4 * q + 3, a23.z, a23.w, f2.y, f2.z, f2.w);
    }
#undef PROC
    __syncthreads();
    int pcnt = s_pcnt; if (pcnt > NPOS) pcnt = NPOS;

    if (tid >= 64) return;                     // selection on wave 0, no barriers

    // 13 rounds of argmax (val desc, anchor asc) == lax.top_k order
    for (int k = 0; k < KK; k++) {
        float bv = 0.0f; int ba = 0x7fffffff; int bp = -1;
        for (int i = tid; i < pcnt; i += 64) {
            float v = s_pv[i];
            if (v > 0.0f) {
                int a = s_pa[i];
                if (v > bv || (v == bv && a < ba)) { bv = v; ba = a; bp = i; }
            }
        }
        for (int off = 32; off > 0; off >>= 1) {
            float v2 = __shfl_xor(bv, off);
            int   a2 = __shfl_xor(ba, off);
            int   p2 = __shfl_xor(bp, off);
            if (v2 > bv || (v2 == bv && a2 < ba)) { bv = v2; ba = a2; bp = p2; }
        }
        if (tid == 0) {
            if (bp >= 0) {
                s_win[k] = ba; s_selv[k] = bv; s_selo[k] = s_po[bp];
                s_pv[bp] = -1.0f;
            } else { s_win[k] = -2; s_selv[k] = 0.0f; s_selo[k] = 0.0f; }
        }
    }

    // zero-fill WITHOUT gathers: met==0  <=>  anchor absent from positive list
    // -> lowest absent indices (lax.top_k zero tie-break)
    int defmask = 0;
    for (int k = 0; k < KK; k++) if (s_win[k] == -2) defmask |= (1 << k);
    if (defmask) {
        int base = 0;
        while (defmask && base < NA) {
            int idx = base + tid;
            bool freez = (idx < NA);
            for (int i = 0; i < pcnt; i++)
                freez = freez && (s_pa[i] != idx);
            unsigned long long msk = __ballot(freez);
            while (msk && defmask) {
                int bit = __ffsll((long long)msk) - 1; msk &= msk - 1;
                int k2  = __ffs(defmask) - 1;          defmask &= defmask - 1;
                if (tid == 0) s_win[k2] = base + bit;   // selv/selo stay 0
            }
            base += 64;
        }
        while (defmask) {
            int k2 = __ffs(defmask) - 1; defmask &= defmask - 1;
            if (tid == 0) s_win[k2] = -1;
        }
    }

    // winners enter mask_pos only if anchor center inside the gt circle
    if (tid < KK) {
        int a = s_win[tid];
        int outv = -1; float om = 0.0f, oo = 0.0f;
        if (a >= 0) {
            float ax = anc[2 * a], ay = anc[2 * a + 1];
            float dx = ax - gx, dy = ay - gy;
            if (sqrtf(dx * dx + dy * dy) < gr) {
                outv = a; om = s_selv[tid]; oo = s_selo[tid];
            }
        }
        wlist[bm * KK + tid] = outv;
        wmet[bm * KK + tid]  = om;
        wov[bm * KK + tid]   = oo;
    }
}

// ---------------------------------------------------------------- K2: winner-slot resolve (32 blocks, dup-scan)

__global__ __launch_bounds__(256)
void k_resolve(const float* __restrict__ pd_scores, const float* __restrict__ pd_circles,
               const float* __restrict__ anc, const int* __restrict__ gt_labels,
               const float* __restrict__ gt_circles, const float* __restrict__ mask_gt,
               const int* __restrict__ wlist, const float* __restrict__ wmet,
               const float* __restrict__ wov,
               int* __restrict__ assigned, float* __restrict__ am_val,
               int* __restrict__ pos_align_i, int* __restrict__ pos_ov_i) {
    int bid  = blockIdx.x;                // 32 = B x 4
    int b    = bid >> 2;
    int part = bid & 3;
    int tid  = threadIdx.x;

    __shared__ int   s_wl[SPB];
    __shared__ float s_wm[SPB], s_wo[SPB];
    __shared__ float s_gx[M], s_gy[M], s_gr[M];
    __shared__ int   s_gl[M], s_act[M];

    if (tid < M) {
        int gi = b * M + tid;
        s_act[tid] = mask_gt[gi] > 0.0f;
        s_gx[tid] = gt_circles[gi * 3 + 0];
        s_gy[tid] = gt_circles[gi * 3 + 1];
        s_gr[tid] = gt_circles[gi * 3 + 2];
        int l = gt_labels[gi];
        s_gl[tid] = l < 0 ? 0 : (l > NC - 1 ? NC - 1 : l);
    }
    for (int i = tid; i < SPB; i += 256) {
        s_wl[i] = wlist[b * SPB + i];
        s_wm[i] = wmet[b * SPB + i];
        s_wo[i] = wov[b * SPB + i];
    }
    __syncthreads();

    int slot = part * (SPB / 4) + tid;    // 208 slots per part
    if (tid >= SPB / 4) return;
    int a = s_wl[slot];
    if (a < 0) return;

    // dup-scan: count + lowest lister slot (deterministic owner)
    int cnt = 0, minslot = SPB;
    for (int i2 = 0; i2 < SPB; i2++)
        if (s_wl[i2] == a) { cnt++; if (i2 < minslot) minslot = i2; }
    if (minslot != slot) return;          // exactly one owner per anchor

    int i = b * NA + a;
    if (cnt == 1) {
        int m = slot / KK;
        assigned[i] = m;
        am_val[i]   = s_wm[slot];
        atomicMax(&pos_align_i[b * M + m], __float_as_int(s_wm[slot]));  // >= 0
        atomicMax(&pos_ov_i[b * M + m],    __float_as_int(s_wo[slot]));
    } else {
        // fg > 1: jnp.argmax over masked overlaps, lowest gt index wins ties
        float ax = anc[2 * a], ay = anc[2 * a + 1];
        float px = pd_circles[(size_t)i * 3 + 0];
        float py = pd_circles[(size_t)i * 3 + 1];
        float pr = pd_circles[(size_t)i * 3 + 2];
        float best = -1.0f; int g = 0;
        for (int mm = 0; mm < M; mm++) {
            float ovv = 0.0f;
            if (s_act[mm]) {
                float gx = s_gx[mm], gy = s_gy[mm], gr = s_gr[mm];
                float dx = ax - gx, dy = ay - gy;
                if (sqrtf(dx * dx + dy * dy) < gr) {
                    float cdx = gx - px, cdy = gy - py;
                    float dc = sqrtf(cdx * cdx + cdy * cdy + 1e-12f);
                    ovv = (dc >= gr + pr) ? 0.0f : circle_iou(gx, gy, gr, px, py, pr);
                }
            }
            if (ovv > best) { best = ovv; g = mm; }
        }
        float met = 0.0f;
        if (best > 0.0f) {
            float sc = pd_scores[(size_t)i * NC + s_gl[g]];
            float o2 = best * best;
            met = sc * (o2 * o2 * o2);
        }
        assigned[i] = g;
        am_val[i]   = met;
        atomicMax(&pos_align_i[b * M + g], __float_as_int(met));
        atomicMax(&pos_ov_i[b * M + g],    __float_as_int(fmaxf(best, 0.0f)));
    }
}

// ---------------------------------------------------------------- K3: fused outputs (93 MB write)

__global__ void k_out(const int* __restrict__ assigned, const float* __restrict__ am_val,
                      const int* __restrict__ pos_align_i, const int* __restrict__ pos_ov_i,
                      const int* __restrict__ gt_labels, const float* __restrict__ gt_circles,
                      float* __restrict__ out_labels, float* __restrict__ out_circ,
                      float* __restrict__ out_scores, float* __restrict__ out_fg,
                      float* __restrict__ out_gtidx) {
    const int QPR = NC / 4;                      // 20 float4s per score row
    int q = blockIdx.x * blockDim.x + threadIdx.x;
    if (q >= B * NA * QPR) return;
    int row = q / QPR;
    int c0  = (q - row * QPR) * 4;
    int b   = row / NA;

    int g = assigned[row];
    int gidx = 0; float fg = 0.0f; float norm = 0.0f;
    if (g >= 0) {
        gidx = g; fg = 1.0f;
        float pa = __int_as_float(pos_align_i[b * M + g]);
        float po = __int_as_float(pos_ov_i[b * M + g]);
        norm = am_val[row] * po / (pa + EPSF);
    }
    int rawl = gt_labels[b * M + gidx];
    int lbl = rawl < 0 ? 0 : rawl;               // clip(.., 0, None)

    float4 v = make_float4(0.f, 0.f, 0.f, 0.f);
    if (g >= 0) {
        int off = lbl - c0;
        if (off >= 0 && off < 4) ((float*)&v)[off] = norm;
    }
    reinterpret_cast<float4*>(out_scores)[q] = v;

    if (c0 == 0) {
        out_labels[row] = (float)lbl;
        out_circ[(size_t)row * 3 + 0] = gt_circles[(b * M + gidx) * 3 + 0];
        out_circ[(size_t)row * 3 + 1] = gt_circles[(b * M + gidx) * 3 + 1];
        out_circ[(size_t)row * 3 + 2] = gt_circles[(b * M + gidx) * 3 + 2];
        out_fg[row]    = fg;
        out_gtidx[row] = (float)gidx;
    }
}

// ---------------------------------------------------------------- launch

extern "C" void kernel_launch(void* const* d_in, const int* in_sizes, int n_in,
                              void* d_out, int out_size, void* d_ws, size_t ws_size,
                              hipStream_t stream) {
    const float* pd_scores  = (const float*)d_in[0];   // (B, NA, NC)
    const float* pd_circles = (const float*)d_in[1];   // (B, NA, 3)
    const float* anc        = (const float*)d_in[2];   // (NA, 2)
    const int*   gt_labels  = (const int*)  d_in[3];   // (B, M, 1)
    const float* gt_circles = (const float*)d_in[4];   // (B, M, 3)
    const float* mask_gt    = (const float*)d_in[5];   // (B, M, 1)

    // workspace layout
    char* w = (char*)d_ws;
    int*   wlist       = (int*)w;   w += (size_t)B * SPB * sizeof(int);
    float* wmetv       = (float*)w; w += (size_t)B * SPB * sizeof(float);
    float* wovv        = (float*)w; w += (size_t)B * SPB * sizeof(float);
    int*   assigned    = (int*)w;   w += (size_t)B * NA * sizeof(int);
    float* am_val      = (float*)w; w += (size_t)B * NA * sizeof(float);
    int*   pos_align_i = (int*)w;   w += (size_t)B * M * sizeof(int);
    int*   pos_ov_i    = (int*)w;   w += (size_t)B * M * sizeof(int);

    // output layout (concat in return order, float32)
    float* out        = (float*)d_out;
    float* out_labels = out;                              // B*NA
    float* out_circ   = out_labels + (size_t)B * NA;      // B*NA*3
    float* out_scores = out_circ + (size_t)B * NA * 3;    // B*NA*NC
    float* out_fg     = out_scores + (size_t)B * NA * NC; // B*NA
    float* out_gtidx  = out_fg + (size_t)B * NA;          // B*NA

    k_discover<<<NBM, 1024, 0, stream>>>(pd_scores, pd_circles, anc, gt_labels,
                                         gt_circles, mask_gt,
                                         wlist, wmetv, wovv,
                                         assigned, am_val, pos_align_i, pos_ov_i);

    k_resolve<<<32, 256, 0, stream>>>(pd_scores, pd_circles, anc, gt_labels,
                                      gt_circles, mask_gt, wlist, wmetv, wovv,
                                      assigned, am_val, pos_align_i, pos_ov_i);

    int nq = B * NA * (NC / 4);
    k_out<<<(nq + 255) / 256, 256, 0, stream>>>(assigned, am_val,
                                                pos_align_i, pos_ov_i,
                                                gt_labels, gt_circles,
                                                out_labels, out_circ, out_scores,
                                                out_fg, out_gtidx);
}

// Round 15
// 82.584 us; speedup vs baseline: 1.3366x; 1.3366x over previous
//
#include <hip/hip_runtime.h>
#include <math.h>

#define B   8
#define NA  33600
#define M   64
#define NC  80
#define KK  13
#define EPSF 1e-9f
#define PIF 3.14159265358979323846f

#define NPOS 1536          // positive-metric capacity (<= in-circle max ~1100)
#define NBM  (B * M)       // 512
#define SPB  (M * KK)      // 832 winner slots per batch

// ---------------------------------------------------------------- helpers

__device__ __forceinline__ float circle_iou(float gx, float gy, float gr,
                                            float px, float py, float pr) {
    float dx = gx - px, dy = gy - py;
    float d  = sqrtf(dx * dx + dy * dy + 1e-12f);
    float r0sq = gr * gr, r1sq = pr * pr;
    float d1 = (r0sq - r1sq + d * d) / (2.0f * d);
    float d2 = d - d1;
    float t0 = fminf(fmaxf(d1 / fmaxf(gr, EPSF), -1.0f), 1.0f);
    float t1 = fminf(fmaxf(d2 / fmaxf(pr, EPSF), -1.0f), 1.0f);
    float a0 = r0sq * acosf(t0) - d1 * sqrtf(fmaxf(r0sq - d1 * d1, 0.0f));
    float a1 = r1sq * acosf(t1) - d2 * sqrtf(fmaxf(r1sq - d2 * d2, 0.0f));
    float lens = a0 + a1;
    float rmin = fminf(gr, pr);
    float contained = PIF * rmin * rmin;
    float inter = (d >= gr + pr) ? 0.0f
                : ((d <= fabsf(gr - pr)) ? contained : lens);
    float uni = PIF * r0sq + PIF * r1sq - inter;
    return (uni > 0.0f) ? inter / uni : 0.0f;
}

// ---------------------------------------------------------------- K1: per-gt dense-stream discovery + top-13
// XCD swizzle: b = bid & 7 -> all blocks of batch b share one XCD's L2,
// making the 3.4 MB batch working set private-L2-resident (was L3-thrash).

__global__ __launch_bounds__(1024)
void k_discover(const float* __restrict__ pd_scores, const float* __restrict__ pd_circles,
                const float* __restrict__ anc, const int* __restrict__ gt_labels,
                const float* __restrict__ gt_circles, const float* __restrict__ mask_gt,
                int* __restrict__ wlist, int* __restrict__ assigned,
                float* __restrict__ am_val) {
    int bid = blockIdx.x;
    int b   = bid & 7;                         // XCD-local batch
    int m   = bid >> 3;
    int bm  = b * M + m;
    int tid = threadIdx.x;

    // init of assigned/am_val (disjoint slice per block)
    const int SL = (B * NA) / NBM;             // 525
    int s0 = bid * SL;
    if (tid < SL) { assigned[s0 + tid] = -1; am_val[s0 + tid] = 0.0f; }

    __shared__ int   s_pcnt;
    __shared__ int   s_pa[NPOS];
    __shared__ float s_pv[NPOS];
    __shared__ int   s_win[KK];

    float gmask = mask_gt[bm];
    if (!(gmask > 0.0f)) {                     // inactive gt: empty winner list
        if (tid < KK) wlist[bm * KK + tid] = -1;
        return;
    }

    float gx = gt_circles[bm * 3 + 0];
    float gy = gt_circles[bm * 3 + 1];
    float gr = gt_circles[bm * 3 + 2];
    int gl = gt_labels[bm];
    gl = gl < 0 ? 0 : (gl > NC - 1 ? NC - 1 : gl);

    if (tid == 0) s_pcnt = 0;
    __syncthreads();

    // dense stream: 2 anchors per iteration; anc float4 + pd 3x float2
    const float2* pdc2 = reinterpret_cast<const float2*>(pd_circles + (size_t)b * NA * 3);
    for (int q = tid; q < NA / 2; q += 1024) {
        float4 ap = reinterpret_cast<const float4*>(anc)[q];   // anchors 2q, 2q+1
        float2 p0 = pdc2[3 * q + 0];   // x0 y0
        float2 p1 = pdc2[3 * q + 1];   // r0 x1
        float2 p2 = pdc2[3 * q + 2];   // y1 r1
        // anchor 2q
        {
            float dx = ap.x - gx, dy = ap.y - gy;
            if (sqrtf(dx * dx + dy * dy) < gr) {               // in-circle
                float px = p0.x, py = p0.y, pr = p1.x;
                float cdx = gx - px, cdy = gy - py;
                float dc = sqrtf(cdx * cdx + cdy * cdy + 1e-12f);
                if (dc < gr + pr) {                            // not disjoint
                    float ov = circle_iou(gx, gy, gr, px, py, pr);  // gmask==1
                    if (ov > 0.0f) {
                        float sc = pd_scores[((size_t)b * NA + 2 * q) * NC + gl];
                        float o2 = ov * ov;
                        float met = sc * (o2 * o2 * o2);       // score^1 * ov^6
                        if (met > 0.0f) {
                            int p = atomicAdd(&s_pcnt, 1);
                            if (p < NPOS) { s_pa[p] = 2 * q; s_pv[p] = met; }
                        }
                    }
                }
            }
        }
        // anchor 2q+1
        {
            float dx = ap.z - gx, dy = ap.w - gy;
            if (sqrtf(dx * dx + dy * dy) < gr) {
                float px = p1.y, py = p2.x, pr = p2.y;
                float cdx = gx - px, cdy = gy - py;
                float dc = sqrtf(cdx * cdx + cdy * cdy + 1e-12f);
                if (dc < gr + pr) {
                    float ov = circle_iou(gx, gy, gr, px, py, pr);
                    if (ov > 0.0f) {
                        float sc = pd_scores[((size_t)b * NA + 2 * q + 1) * NC + gl];
                        float o2 = ov * ov;
                        float met = sc * (o2 * o2 * o2);
                        if (met > 0.0f) {
                            int p = atomicAdd(&s_pcnt, 1);
                            if (p < NPOS) { s_pa[p] = 2 * q + 1; s_pv[p] = met; }
                        }
                    }
                }
            }
        }
    }
    __syncthreads();
    int pcnt = s_pcnt; if (pcnt > NPOS) pcnt = NPOS;

    if (tid >= 64) return;                     // selection on wave 0, no barriers

    // 13 rounds of argmax (val desc, anchor asc) == lax.top_k order
    for (int k = 0; k < KK; k++) {
        float bv = 0.0f; int ba = 0x7fffffff; int bp = -1;
        for (int i = tid; i < pcnt; i += 64) {
            float v = s_pv[i];
            if (v > 0.0f) {
                int a = s_pa[i];
                if (v > bv || (v == bv && a < ba)) { bv = v; ba = a; bp = i; }
            }
        }
        for (int off = 32; off > 0; off >>= 1) {
            float v2 = __shfl_xor(bv, off);
            int   a2 = __shfl_xor(ba, off);
            int   p2 = __shfl_xor(bp, off);
            if (v2 > bv || (v2 == bv && a2 < ba)) { bv = v2; ba = a2; bp = p2; }
        }
        if (tid == 0) {
            if (bp >= 0) { s_win[k] = ba; s_pv[bp] = -1.0f; }
            else s_win[k] = -2;
        }
    }

    // zero-fill WITHOUT gathers: met==0  <=>  anchor absent from positive list
    // -> lowest absent indices (lax.top_k zero tie-break)
    int defmask = 0;
    for (int k = 0; k < KK; k++) if (s_win[k] == -2) defmask |= (1 << k);
    if (defmask) {
        int base = 0;
        while (defmask && base < NA) {
            int idx = base + tid;
            bool freez = (idx < NA);
            for (int i = 0; i < pcnt; i++)
                freez = freez && (s_pa[i] != idx);
            unsigned long long msk = __ballot(freez);
            while (msk && defmask) {
                int bit = __ffsll((long long)msk) - 1; msk &= msk - 1;
                int k2  = __ffs(defmask) - 1;          defmask &= defmask - 1;
                if (tid == 0) s_win[k2] = base + bit;
            }
            base += 64;
        }
        while (defmask) {
            int k2 = __ffs(defmask) - 1; defmask &= defmask - 1;
            if (tid == 0) s_win[k2] = -1;
        }
    }

    // winners enter mask_pos only if anchor center inside the gt circle
    if (tid < KK) {
        int a = s_win[tid];
        int outv = -1;
        if (a >= 0) {
            float ax = anc[2 * a], ay = anc[2 * a + 1];
            float dx = ax - gx, dy = ay - gy;
            if (sqrtf(dx * dx + dy * dy) < gr) outv = a;
        }
        wlist[bm * KK + tid] = outv;
    }
}

// ---------------------------------------------------------------- K2: per-batch resolve + pos maxima
// LDS u8 histogram over the 832 winner slots (no pre-zeroed global needed).

__global__ __launch_bounds__(1024)
void k_resolve(const float* __restrict__ pd_scores, const float* __restrict__ pd_circles,
               const float* __restrict__ anc, const int* __restrict__ gt_labels,
               const float* __restrict__ gt_circles, const float* __restrict__ mask_gt,
               const int* __restrict__ wlist,
               int* __restrict__ assigned, float* __restrict__ am_val,
               int* __restrict__ pos_align_i, int* __restrict__ pos_ov_i) {
    int b = blockIdx.x;
    int tid = threadIdx.x;

    __shared__ unsigned int s_cnt[NA / 4 + 1];   // u8-packed counts, 33.6 KB
    __shared__ float s_gx[M], s_gy[M], s_gr[M];
    __shared__ int   s_gl[M], s_act[M];
    __shared__ int   s_posa[M], s_poso[M];
    __shared__ int   s_multi[512];
    __shared__ int   s_nm;

    if (tid < M) {
        int gi = b * M + tid;
        s_act[tid] = mask_gt[gi] > 0.0f;
        s_gx[tid] = gt_circles[gi * 3 + 0];
        s_gy[tid] = gt_circles[gi * 3 + 1];
        s_gr[tid] = gt_circles[gi * 3 + 2];
        int l = gt_labels[gi];
        s_gl[tid] = l < 0 ? 0 : (l > NC - 1 ? NC - 1 : l);
        s_posa[tid] = 0; s_poso[tid] = 0;
    }
    if (tid == 0) s_nm = 0;
    for (int w = tid; w < NA / 4 + 1; w += 1024) s_cnt[w] = 0;
    __syncthreads();

    // histogram: count gts listing each anchor (in-circle-filtered winners)
    int a = -1, m = -1; unsigned int prev = 0;
    if (tid < SPB) {
        a = wlist[b * SPB + tid];
        m = tid / KK;
        if (a >= 0) {
            unsigned int sh = 8u * (a & 3);
            unsigned int old = atomicAdd(&s_cnt[a >> 2], 1u << sh);
            prev = (old >> sh) & 0xFFu;          // my slot's order among dupes
        }
    }
    __syncthreads();

    // classify; singles resolve immediately; first-toucher of multis enqueues
    bool single = false;
    if (a >= 0) {
        unsigned int c = (s_cnt[a >> 2] >> (8u * (a & 3))) & 0xFFu;
        if (c == 1u) single = true;
        else if (prev == 0u) { int i2 = atomicAdd(&s_nm, 1); s_multi[i2] = a; }
    }
    if (single) {
        int i = b * NA + a;
        float gx = s_gx[m], gy = s_gy[m], gr = s_gr[m];
        float px = pd_circles[(size_t)i * 3 + 0];
        float py = pd_circles[(size_t)i * 3 + 1];
        float pr = pd_circles[(size_t)i * 3 + 2];
        float cdx = gx - px, cdy = gy - py;
        float dc = sqrtf(cdx * cdx + cdy * cdy + 1e-12f);
        float ov = (dc >= gr + pr) ? 0.0f : circle_iou(gx, gy, gr, px, py, pr);
        float met = 0.0f;
        if (ov > 0.0f) {
            float sc = pd_scores[(size_t)i * NC + s_gl[m]];
            float o2 = ov * ov;
            met = sc * (o2 * o2 * o2);
        }
        assigned[i] = m;
        am_val[i]   = met;
        atomicMax(&s_posa[m], __float_as_int(met));   // values >= 0
        atomicMax(&s_poso[m], __float_as_int(ov));
    }
    __syncthreads();

    // multis: one anchor per wave; lane = gt; argmax over masked overlaps
    // (jnp.argmax semantics: lowest gt index wins ties; all-zero row -> 0)
    int lane = tid & 63, w = tid >> 6;           // 16 waves
    int nm = s_nm;
    for (int r = w; r < nm; r += 16) {
        int am_ = s_multi[r];
        int i = b * NA + am_;
        float ax = anc[2 * am_], ay = anc[2 * am_ + 1];
        float px = pd_circles[(size_t)i * 3 + 0];
        float py = pd_circles[(size_t)i * 3 + 1];
        float pr = pd_circles[(size_t)i * 3 + 2];
        float ov = 0.0f;
        if (s_act[lane]) {
            float gx = s_gx[lane], gy = s_gy[lane], gr = s_gr[lane];
            float dx = ax - gx, dy = ay - gy;
            if (sqrtf(dx * dx + dy * dy) < gr) {
                float cdx = gx - px, cdy = gy - py;
                float dc = sqrtf(cdx * cdx + cdy * cdy + 1e-12f);
                ov = (dc >= gr + pr) ? 0.0f : circle_iou(gx, gy, gr, px, py, pr);
            }
        }
        float bv = ov; int bmx = lane;
        for (int off = 32; off > 0; off >>= 1) {
            float v2 = __shfl_xor(bv, off);
            int   m2 = __shfl_xor(bmx, off);
            if (v2 > bv || (v2 == bv && m2 < bmx)) { bv = v2; bmx = m2; }
        }
        if (lane == 0) {
            float met = 0.0f;
            if (bv > 0.0f) {
                float sc = pd_scores[(size_t)i * NC + s_gl[bmx]];
                float o2 = bv * bv;
                met = sc * (o2 * o2 * o2);
            }
            assigned[i] = bmx;
            am_val[i]   = met;
            atomicMax(&s_posa[bmx], __float_as_int(met));
            atomicMax(&s_poso[bmx], __float_as_int(bv));
        }
    }
    __syncthreads();

    if (tid < M) {
        pos_align_i[b * M + tid] = s_posa[tid];
        pos_ov_i[b * M + tid]    = s_poso[tid];
    }
}

// ---------------------------------------------------------------- K3: fused outputs (93 MB write)

__global__ void k_out(const int* __restrict__ assigned, const float* __restrict__ am_val,
                      const int* __restrict__ pos_align_i, const int* __restrict__ pos_ov_i,
                      const int* __restrict__ gt_labels, const float* __restrict__ gt_circles,
                      float* __restrict__ out_labels, float* __restrict__ out_circ,
                      float* __restrict__ out_scores, float* __restrict__ out_fg,
                      float* __restrict__ out_gtidx) {
    const int QPR = NC / 4;                      // 20 float4s per score row
    int q = blockIdx.x * blockDim.x + threadIdx.x;
    if (q >= B * NA * QPR) return;
    int row = q / QPR;
    int c0  = (q - row * QPR) * 4;
    int b   = row / NA;

    int g = assigned[row];
    int gidx = 0; float fg = 0.0f; float norm = 0.0f;
    if (g >= 0) {
        gidx = g; fg = 1.0f;
        float pa = __int_as_float(pos_align_i[b * M + g]);
        float po = __int_as_float(pos_ov_i[b * M + g]);
        norm = am_val[row] * po / (pa + EPSF);
    }
    int rawl = gt_labels[b * M + gidx];
    int lbl = rawl < 0 ? 0 : rawl;               // clip(.., 0, None)

    float4 v = make_float4(0.f, 0.f, 0.f, 0.f);
    if (g >= 0) {
        int off = lbl - c0;
        if (off >= 0 && off < 4) ((float*)&v)[off] = norm;
    }
    reinterpret_cast<float4*>(out_scores)[q] = v;

    if (c0 == 0) {
        out_labels[row] = (float)lbl;
        out_circ[(size_t)row * 3 + 0] = gt_circles[(b * M + gidx) * 3 + 0];
        out_circ[(size_t)row * 3 + 1] = gt_circles[(b * M + gidx) * 3 + 1];
        out_circ[(size_t)row * 3 + 2] = gt_circles[(b * M + gidx) * 3 + 2];
        out_fg[row]    = fg;
        out_gtidx[row] = (float)gidx;
    }
}

// ---------------------------------------------------------------- launch

extern "C" void kernel_launch(void* const* d_in, const int* in_sizes, int n_in,
                              void* d_out, int out_size, void* d_ws, size_t ws_size,
                              hipStream_t stream) {
    const float* pd_scores  = (const float*)d_in[0];   // (B, NA, NC)
    const float* pd_circles = (const float*)d_in[1];   // (B, NA, 3)
    const float* anc        = (const float*)d_in[2];   // (NA, 2)
    const int*   gt_labels  = (const int*)  d_in[3];   // (B, M, 1)
    const float* gt_circles = (const float*)d_in[4];   // (B, M, 3)
    const float* mask_gt    = (const float*)d_in[5];   // (B, M, 1)

    // workspace layout
    char* w = (char*)d_ws;
    int*   wlist       = (int*)w;   w += (size_t)NBM * KK * sizeof(int);
    int*   assigned    = (int*)w;   w += (size_t)B * NA * sizeof(int);
    float* am_val      = (float*)w; w += (size_t)B * NA * sizeof(float);
    int*   pos_align_i = (int*)w;   w += (size_t)B * M * sizeof(int);
    int*   pos_ov_i    = (int*)w;   w += (size_t)B * M * sizeof(int);

    // output layout (concat in return order, float32)
    float* out        = (float*)d_out;
    float* out_labels = out;                              // B*NA
    float* out_circ   = out_labels + (size_t)B * NA;      // B*NA*3
    float* out_scores = out_circ + (size_t)B * NA * 3;    // B*NA*NC
    float* out_fg     = out_scores + (size_t)B * NA * NC; // B*NA
    float* out_gtidx  = out_fg + (size_t)B * NA;          // B*NA

    k_discover<<<NBM, 1024, 0, stream>>>(pd_scores, pd_circles, anc, gt_labels,
                                         gt_circles, mask_gt,
                                         wlist, assigned, am_val);

    k_resolve<<<B, 1024, 0, stream>>>(pd_scores, pd_circles, anc, gt_labels,
                                      gt_circles, mask_gt, wlist,
                                      assigned, am_val, pos_align_i, pos_ov_i);

    int nq = B * NA * (NC / 4);
    k_out<<<(nq + 255) / 256, 256, 0, stream>>>(assigned, am_val,
                                                pos_align_i, pos_ov_i,
                                                gt_labels, gt_circles,
                                                out_labels, out_circ, out_scores,
                                                out_fg, out_gtidx);
}

// Round 16
// 73.777 us; speedup vs baseline: 1.4961x; 1.1194x over previous
//
#include <hip/hip_runtime.h>
#include <math.h>

#define B   8
#define NA  33600
#define M   64
#define NC  80
#define KK  13
#define EPSF 1e-9f
#define PIF 3.14159265358979323846f

#define NPOS 1536          // in-circle / positive capacity (max in-circle ~1100)
#define NBM  (B * M)       // 512
#define SPB  (M * KK)      // 832 winner slots per batch

// ---------------------------------------------------------------- helpers

__device__ __forceinline__ float circle_iou(float gx, float gy, float gr,
                                            float px, float py, float pr) {
    float dx = gx - px, dy = gy - py;
    float d  = sqrtf(dx * dx + dy * dy + 1e-12f);
    float r0sq = gr * gr, r1sq = pr * pr;
    float d1 = (r0sq - r1sq + d * d) / (2.0f * d);
    float d2 = d - d1;
    float t0 = fminf(fmaxf(d1 / fmaxf(gr, EPSF), -1.0f), 1.0f);
    float t1 = fminf(fmaxf(d2 / fmaxf(pr, EPSF), -1.0f), 1.0f);
    float a0 = r0sq * acosf(t0) - d1 * sqrtf(fmaxf(r0sq - d1 * d1, 0.0f));
    float a1 = r1sq * acosf(t1) - d2 * sqrtf(fmaxf(r1sq - d2 * d2, 0.0f));
    float lens = a0 + a1;
    float rmin = fminf(gr, pr);
    float contained = PIF * rmin * rmin;
    float inter = (d >= gr + pr) ? 0.0f
                : ((d <= fabsf(gr - pr)) ? contained : lens);
    float uni = PIF * r0sq + PIF * r1sq - inter;
    return (uni > 0.0f) ? inter / uni : 0.0f;
}

// ---------------------------------------------------------------- K1: per-gt two-phase discovery + top-13
// Phase A: anc-only in-circle scan (1 float4 load / 2 anchors -> 4x fewer
// VMEM issues than the dense pd stream). Phase B: dense loop over the ~375
// compacted candidates with scattered (L2-resident) pd loads.

__global__ __launch_bounds__(1024)
void k_discover(const float* __restrict__ pd_scores, const float* __restrict__ pd_circles,
                const float* __restrict__ anc, const int* __restrict__ gt_labels,
                const float* __restrict__ gt_circles, const float* __restrict__ mask_gt,
                int* __restrict__ wlist, int* __restrict__ assigned,
                float* __restrict__ am_val) {
    int bid = blockIdx.x;
    int b   = bid & 7;                         // XCD-local batch
    int m   = bid >> 3;
    int bm  = b * M + m;
    int tid = threadIdx.x;

    // init of assigned/am_val (disjoint slice per block)
    const int SL = (B * NA) / NBM;             // 525
    int s0 = bid * SL;
    if (tid < SL) { assigned[s0 + tid] = -1; am_val[s0 + tid] = 0.0f; }

    __shared__ int   s_ccnt, s_pcnt;
    __shared__ int   s_ca[NPOS];               // in-circle candidates
    __shared__ int   s_pa[NPOS];               // positive-metric anchors
    __shared__ float s_pv[NPOS];
    __shared__ int   s_win[KK];

    float gmask = mask_gt[bm];
    if (!(gmask > 0.0f)) {                     // inactive gt: empty winner list
        if (tid < KK) wlist[bm * KK + tid] = -1;
        return;
    }

    float gx = gt_circles[bm * 3 + 0];
    float gy = gt_circles[bm * 3 + 1];
    float gr = gt_circles[bm * 3 + 2];
    int gl = gt_labels[bm];
    gl = gl < 0 ? 0 : (gl > NC - 1 ? NC - 1 : gl);

    if (tid == 0) { s_ccnt = 0; s_pcnt = 0; }
    __syncthreads();

    // ---- phase A: anc-only in-circle scan (pure stream, no pd loads)
    for (int q = tid; q < NA / 2; q += 1024) {
        float4 ap = reinterpret_cast<const float4*>(anc)[q];   // anchors 2q, 2q+1
        float dx0 = ap.x - gx, dy0 = ap.y - gy;
        float dx1 = ap.z - gx, dy1 = ap.w - gy;
        bool h0 = sqrtf(dx0 * dx0 + dy0 * dy0) < gr;
        bool h1 = sqrtf(dx1 * dx1 + dy1 * dy1) < gr;
        if (h0) { int p = atomicAdd(&s_ccnt, 1); if (p < NPOS) s_ca[p] = 2 * q; }
        if (h1) { int p = atomicAdd(&s_ccnt, 1); if (p < NPOS) s_ca[p] = 2 * q + 1; }
    }
    __syncthreads();
    int ccnt = s_ccnt; if (ccnt > NPOS) ccnt = NPOS;

    // ---- phase B: dense metric over candidates (scattered pd loads, L2-local)
    for (int i = tid; i < ccnt; i += 1024) {
        int a = s_ca[i];
        size_t pb = ((size_t)b * NA + a) * 3;
        float px = pd_circles[pb + 0];
        float py = pd_circles[pb + 1];
        float pr = pd_circles[pb + 2];
        float cdx = gx - px, cdy = gy - py;
        float dc = sqrtf(cdx * cdx + cdy * cdy + 1e-12f);
        if (dc >= gr + pr) continue;           // disjoint -> iou 0 -> met 0
        float ov = circle_iou(gx, gy, gr, px, py, pr);        // gmask == 1 here
        if (!(ov > 0.0f)) continue;
        float sc = pd_scores[((size_t)b * NA + a) * NC + gl]; // rare gather
        float o2 = ov * ov;
        float met = sc * (o2 * o2 * o2);       // score^1 * ov^6
        if (met > 0.0f) {
            int p = atomicAdd(&s_pcnt, 1);     // p < ccnt <= NPOS guaranteed
            s_pa[p] = a; s_pv[p] = met;
        }
    }
    __syncthreads();
    int pcnt = s_pcnt;

    if (tid >= 64) return;                     // selection on wave 0, no barriers

    // 13 rounds of argmax (val desc, anchor asc) == lax.top_k order
    for (int k = 0; k < KK; k++) {
        float bv = 0.0f; int ba = 0x7fffffff; int bp = -1;
        for (int i = tid; i < pcnt; i += 64) {
            float v = s_pv[i];
            if (v > 0.0f) {
                int a = s_pa[i];
                if (v > bv || (v == bv && a < ba)) { bv = v; ba = a; bp = i; }
            }
        }
        for (int off = 32; off > 0; off >>= 1) {
            float v2 = __shfl_xor(bv, off);
            int   a2 = __shfl_xor(ba, off);
            int   p2 = __shfl_xor(bp, off);
            if (v2 > bv || (v2 == bv && a2 < ba)) { bv = v2; ba = a2; bp = p2; }
        }
        if (tid == 0) {
            if (bp >= 0) { s_win[k] = ba; s_pv[bp] = -1.0f; }
            else s_win[k] = -2;
        }
    }

    // zero-fill WITHOUT gathers: met==0  <=>  anchor absent from positive list
    // -> lowest absent indices (lax.top_k zero tie-break)
    int defmask = 0;
    for (int k = 0; k < KK; k++) if (s_win[k] == -2) defmask |= (1 << k);
    if (defmask) {
        int base = 0;
        while (defmask && base < NA) {
            int idx = base + tid;
            bool freez = (idx < NA);
            for (int i = 0; i < pcnt; i++)
                freez = freez && (s_pa[i] != idx);
            unsigned long long msk = __ballot(freez);
            while (msk && defmask) {
                int bit = __ffsll((long long)msk) - 1; msk &= msk - 1;
                int k2  = __ffs(defmask) - 1;          defmask &= defmask - 1;
                if (tid == 0) s_win[k2] = base + bit;
            }
            base += 64;
        }
        while (defmask) {
            int k2 = __ffs(defmask) - 1; defmask &= defmask - 1;
            if (tid == 0) s_win[k2] = -1;
        }
    }

    // winners enter mask_pos only if anchor center inside the gt circle
    if (tid < KK) {
        int a = s_win[tid];
        int outv = -1;
        if (a >= 0) {
            float ax = anc[2 * a], ay = anc[2 * a + 1];
            float dx = ax - gx, dy = ay - gy;
            if (sqrtf(dx * dx + dy * dy) < gr) outv = a;
        }
        wlist[bm * KK + tid] = outv;
    }
}

// ---------------------------------------------------------------- K2: per-batch resolve + pos maxima
// LDS u8 histogram over the 832 winner slots (no pre-zeroed global needed).

__global__ __launch_bounds__(1024)
void k_resolve(const float* __restrict__ pd_scores, const float* __restrict__ pd_circles,
               const float* __restrict__ anc, const int* __restrict__ gt_labels,
               const float* __restrict__ gt_circles, const float* __restrict__ mask_gt,
               const int* __restrict__ wlist,
               int* __restrict__ assigned, float* __restrict__ am_val,
               int* __restrict__ pos_align_i, int* __restrict__ pos_ov_i) {
    int b = blockIdx.x;
    int tid = threadIdx.x;

    __shared__ unsigned int s_cnt[NA / 4 + 1];   // u8-packed counts, 33.6 KB
    __shared__ float s_gx[M], s_gy[M], s_gr[M];
    __shared__ int   s_gl[M], s_act[M];
    __shared__ int   s_posa[M], s_poso[M];
    __shared__ int   s_multi[512];
    __shared__ int   s_nm;

    if (tid < M) {
        int gi = b * M + tid;
        s_act[tid] = mask_gt[gi] > 0.0f;
        s_gx[tid] = gt_circles[gi * 3 + 0];
        s_gy[tid] = gt_circles[gi * 3 + 1];
        s_gr[tid] = gt_circles[gi * 3 + 2];
        int l = gt_labels[gi];
        s_gl[tid] = l < 0 ? 0 : (l > NC - 1 ? NC - 1 : l);
        s_posa[tid] = 0; s_poso[tid] = 0;
    }
    if (tid == 0) s_nm = 0;
    for (int w = tid; w < NA / 4 + 1; w += 1024) s_cnt[w] = 0;
    __syncthreads();

    // histogram: count gts listing each anchor (in-circle-filtered winners)
    int a = -1, m = -1; unsigned int prev = 0;
    if (tid < SPB) {
        a = wlist[b * SPB + tid];
        m = tid / KK;
        if (a >= 0) {
            unsigned int sh = 8u * (a & 3);
            unsigned int old = atomicAdd(&s_cnt[a >> 2], 1u << sh);
            prev = (old >> sh) & 0xFFu;          // my slot's order among dupes
        }
    }
    __syncthreads();

    // classify; singles resolve immediately; first-toucher of multis enqueues
    bool single = false;
    if (a >= 0) {
        unsigned int c = (s_cnt[a >> 2] >> (8u * (a & 3))) & 0xFFu;
        if (c == 1u) single = true;
        else if (prev == 0u) { int i2 = atomicAdd(&s_nm, 1); s_multi[i2] = a; }
    }
    if (single) {
        int i = b * NA + a;
        float gx = s_gx[m], gy = s_gy[m], gr = s_gr[m];
        float px = pd_circles[(size_t)i * 3 + 0];
        float py = pd_circles[(size_t)i * 3 + 1];
        float pr = pd_circles[(size_t)i * 3 + 2];
        float cdx = gx - px, cdy = gy - py;
        float dc = sqrtf(cdx * cdx + cdy * cdy + 1e-12f);
        float ov = (dc >= gr + pr) ? 0.0f : circle_iou(gx, gy, gr, px, py, pr);
        float met = 0.0f;
        if (ov > 0.0f) {
            float sc = pd_scores[(size_t)i * NC + s_gl[m]];
            float o2 = ov * ov;
            met = sc * (o2 * o2 * o2);
        }
        assigned[i] = m;
        am_val[i]   = met;
        atomicMax(&s_posa[m], __float_as_int(met));   // values >= 0
        atomicMax(&s_poso[m], __float_as_int(ov));
    }
    __syncthreads();

    // multis: one anchor per wave; lane = gt; argmax over masked overlaps
    // (jnp.argmax semantics: lowest gt index wins ties; all-zero row -> 0)
    int lane = tid & 63, w = tid >> 6;           // 16 waves
    int nm = s_nm;
    for (int r = w; r < nm; r += 16) {
        int am_ = s_multi[r];
        int i = b * NA + am_;
        float ax = anc[2 * am_], ay = anc[2 * am_ + 1];
        float px = pd_circles[(size_t)i * 3 + 0];
        float py = pd_circles[(size_t)i * 3 + 1];
        float pr = pd_circles[(size_t)i * 3 + 2];
        float ov = 0.0f;
        if (s_act[lane]) {
            float gx = s_gx[lane], gy = s_gy[lane], gr = s_gr[lane];
            float dx = ax - gx, dy = ay - gy;
            if (sqrtf(dx * dx + dy * dy) < gr) {
                float cdx = gx - px, cdy = gy - py;
                float dc = sqrtf(cdx * cdx + cdy * cdy + 1e-12f);
                ov = (dc >= gr + pr) ? 0.0f : circle_iou(gx, gy, gr, px, py, pr);
            }
        }
        float bv = ov; int bmx = lane;
        for (int off = 32; off > 0; off >>= 1) {
            float v2 = __shfl_xor(bv, off);
            int   m2 = __shfl_xor(bmx, off);
            if (v2 > bv || (v2 == bv && m2 < bmx)) { bv = v2; bmx = m2; }
        }
        if (lane == 0) {
            float met = 0.0f;
            if (bv > 0.0f) {
                float sc = pd_scores[(size_t)i * NC + s_gl[bmx]];
                float o2 = bv * bv;
                met = sc * (o2 * o2 * o2);
            }
            assigned[i] = bmx;
            am_val[i]   = met;
            atomicMax(&s_posa[bmx], __float_as_int(met));
            atomicMax(&s_poso[bmx], __float_as_int(bv));
        }
    }
    __syncthreads();

    if (tid < M) {
        pos_align_i[b * M + tid] = s_posa[tid];
        pos_ov_i[b * M + tid]    = s_poso[tid];
    }
}

// ---------------------------------------------------------------- K3: fused outputs (93 MB write)

__global__ void k_out(const int* __restrict__ assigned, const float* __restrict__ am_val,
                      const int* __restrict__ pos_align_i, const int* __restrict__ pos_ov_i,
                      const int* __restrict__ gt_labels, const float* __restrict__ gt_circles,
                      float* __restrict__ out_labels, float* __restrict__ out_circ,
                      float* __restrict__ out_scores, float* __restrict__ out_fg,
                      float* __restrict__ out_gtidx) {
    const int QPR = NC / 4;                      // 20 float4s per score row
    int q = blockIdx.x * blockDim.x + threadIdx.x;
    if (q >= B * NA * QPR) return;
    int row = q / QPR;
    int c0  = (q - row * QPR) * 4;
    int b   = row / NA;

    int g = assigned[row];
    int gidx = 0; float fg = 0.0f; float norm = 0.0f;
    if (g >= 0) {
        gidx = g; fg = 1.0f;
        float pa = __int_as_float(pos_align_i[b * M + g]);
        float po = __int_as_float(pos_ov_i[b * M + g]);
        norm = am_val[row] * po / (pa + EPSF);
    }
    int rawl = gt_labels[b * M + gidx];
    int lbl = rawl < 0 ? 0 : rawl;               // clip(.., 0, None)

    float4 v = make_float4(0.f, 0.f, 0.f, 0.f);
    if (g >= 0) {
        int off = lbl - c0;
        if (off >= 0 && off < 4) ((float*)&v)[off] = norm;
    }
    reinterpret_cast<float4*>(out_scores)[q] = v;

    if (c0 == 0) {
        out_labels[row] = (float)lbl;
        out_circ[(size_t)row * 3 + 0] = gt_circles[(b * M + gidx) * 3 + 0];
        out_circ[(size_t)row * 3 + 1] = gt_circles[(b * M + gidx) * 3 + 1];
        out_circ[(size_t)row * 3 + 2] = gt_circles[(b * M + gidx) * 3 + 2];
        out_fg[row]    = fg;
        out_gtidx[row] = (float)gidx;
    }
}

// ---------------------------------------------------------------- launch

extern "C" void kernel_launch(void* const* d_in, const int* in_sizes, int n_in,
                              void* d_out, int out_size, void* d_ws, size_t ws_size,
                              hipStream_t stream) {
    const float* pd_scores  = (const float*)d_in[0];   // (B, NA, NC)
    const float* pd_circles = (const float*)d_in[1];   // (B, NA, 3)
    const float* anc        = (const float*)d_in[2];   // (NA, 2)
    const int*   gt_labels  = (const int*)  d_in[3];   // (B, M, 1)
    const float* gt_circles = (const float*)d_in[4];   // (B, M, 3)
    const float* mask_gt    = (const float*)d_in[5];   // (B, M, 1)

    // workspace layout
    char* w = (char*)d_ws;
    int*   wlist       = (int*)w;   w += (size_t)NBM * KK * sizeof(int);
    int*   assigned    = (int*)w;   w += (size_t)B * NA * sizeof(int);
    float* am_val      = (float*)w; w += (size_t)B * NA * sizeof(float);
    int*   pos_align_i = (int*)w;   w += (size_t)B * M * sizeof(int);
    int*   pos_ov_i    = (int*)w;   w += (size_t)B * M * sizeof(int);

    // output layout (concat in return order, float32)
    float* out        = (float*)d_out;
    float* out_labels = out;                              // B*NA
    float* out_circ   = out_labels + (size_t)B * NA;      // B*NA*3
    float* out_scores = out_circ + (size_t)B * NA * 3;    // B*NA*NC
    float* out_fg     = out_scores + (size_t)B * NA * NC; // B*NA
    float* out_gtidx  = out_fg + (size_t)B * NA;          // B*NA

    k_discover<<<NBM, 1024, 0, stream>>>(pd_scores, pd_circles, anc, gt_labels,
                                         gt_circles, mask_gt,
                                         wlist, assigned, am_val);

    k_resolve<<<B, 1024, 0, stream>>>(pd_scores, pd_circles, anc, gt_labels,
                                      gt_circles, mask_gt, wlist,
                                      assigned, am_val, pos_align_i, pos_ov_i);

    int nq = B * NA * (NC / 4);
    k_out<<<(nq + 255) / 256, 256, 0, stream>>>(assigned, am_val,
                                                pos_align_i, pos_ov_i,
                                                gt_labels, gt_circles,
                                                out_labels, out_circ, out_scores,
                                                out_fg, out_gtidx);
}